// Round 2
// baseline (246.626 us; speedup 1.0000x reference)
//
#include <hip/hip_runtime.h>
#include <hip/hip_bf16.h>
#include <stdint.h>

#define DI __device__ __forceinline__

using f32x4 = __attribute__((ext_vector_type(4))) float;
using s16x8 = __attribute__((ext_vector_type(8))) short;

#define BB 64
#define SS 400
#define HH 512
#define VVOC 32000
#define MTOT (BB*SS)   // 25600

// ---------- helpers ----------
DI short bf16r(float f){
  __hip_bfloat16 h = __float2bfloat16(f);
  union { __hip_bfloat16 h; short s; } u; u.h = h; return u.s;
}
DI float sigm(float x){ return 1.f/(1.f + __expf(-x)); }
DI float tanhfast(float x){ x = fminf(x, 12.f); float e = __expf(2.f*x); return (e-1.f)/(e+1.f); }

DI void gload16(const float* g, float* l){
  __builtin_amdgcn_global_load_lds(
      (const __attribute__((address_space(1))) float*)g,
      (__attribute__((address_space(3))) float*)l, 16, 0, 0);
}
DI void gload16b(const __hip_bfloat16* g, short* l){
  __builtin_amdgcn_global_load_lds(
      (const __attribute__((address_space(1))) __hip_bfloat16*)g,
      (__attribute__((address_space(3))) short*)l, 16, 0, 0);
}

DI float blkmax(float v, float* red, int t){
  #pragma unroll
  for (int o = 32; o; o >>= 1) v = fmaxf(v, __shfl_xor(v, o));
  if ((t & 63) == 0) red[t >> 6] = v;
  __syncthreads();
  v = fmaxf(fmaxf(red[0], red[1]), fmaxf(red[2], red[3]));
  __syncthreads();
  return v;
}
DI float blksum(float v, float* red, int t){
  #pragma unroll
  for (int o = 32; o; o >>= 1) v += __shfl_xor(v, o);
  if ((t & 63) == 0) red[t >> 6] = v;
  __syncthreads();
  v = red[0] + red[1] + red[2] + red[3];
  __syncthreads();
  return v;
}

// ---------- f32 -> bf16 streaming convert (8 elems/thread/iter) ----------
__global__ __launch_bounds__(256) void cvt_bf16(const float* __restrict__ src,
                                                short* __restrict__ dst, int n8){
  int i = blockIdx.x*256 + threadIdx.x;
  int stride = gridDim.x*256;
  for (; i < n8; i += stride) {
    f32x4 a = ((const f32x4*)src)[2*i];
    f32x4 b = ((const f32x4*)src)[2*i+1];
    s16x8 o;
    o[0]=bf16r(a[0]); o[1]=bf16r(a[1]); o[2]=bf16r(a[2]); o[3]=bf16r(a[3]);
    o[4]=bf16r(b[0]); o[5]=bf16r(b[1]); o[6]=bf16r(b[2]); o[7]=bf16r(b[3]);
    ((s16x8*)dst)[i] = o;
  }
}

// fragment load from f32 LDS tile (row stride 32 floats, 16B chunks XOR-swizzled by row&7)
DI s16x8 fragload(const float* tile, int rbase, int l){
  int kq = l >> 4;
  int rr = rbase + (l & 15);
  int swz = rr & 7;
  const float* base = tile + rr*32;
  f32x4 lo = *(const f32x4*)(base + (((2*kq    ) ^ swz) << 2));
  f32x4 hi = *(const f32x4*)(base + (((2*kq + 1) ^ swz) << 2));
  s16x8 o;
  o[0]=bf16r(lo[0]); o[1]=bf16r(lo[1]); o[2]=bf16r(lo[2]); o[3]=bf16r(lo[3]);
  o[4]=bf16r(hi[0]); o[5]=bf16r(hi[1]); o[6]=bf16r(hi[2]); o[7]=bf16r(hi[3]);
  return o;
}

// bf16 LDS tile: row stride 64 shorts (128B), 8 chunks of 16B, slot = chunk ^ (row&7)
DI s16x8 fragload16(const short* tile, int rbase, int kk, int l){
  int r = rbase + (l & 15);
  int c = (kk >> 3) + (l >> 4);
  int slot = c ^ (r & 7);
  return *(const s16x8*)(tile + r*64 + slot*8);
}

// ---------- mask dtype detector (bool bytes vs int32) ----------
__global__ void detect_mask(const unsigned int* m, int nwords, int* flag){
  __shared__ int f;
  if (threadIdx.x == 0) f = 0;
  __syncthreads();
  int loc = 0;
  for (int i = threadIdx.x; i < nwords; i += blockDim.x) loc |= (m[i] > 1u) ? 1 : 0;
  if (loc) atomicOr(&f, 1);
  __syncthreads();
  if (threadIdx.x == 0) *flag = f;
}

// ---------- bf16 score GEMM: A[25600,1024] * Wh[512,1024]^T, fused tanh-dot epilogue ----------
__global__ __launch_bounds__(256) void score_gemm_bf16(
    const __hip_bfloat16* __restrict__ A, const __hip_bfloat16* __restrict__ Bw,
    const float* __restrict__ qv, const float* __restrict__ vb, float* __restrict__ dst)
{
  __shared__ __align__(16) short lsa[128*64];
  __shared__ __align__(16) short lsb[128*64];
  const int t = threadIdx.x;
  const int l = t & 63;
  const int w = t >> 6;
  const int wm = w >> 1, wn = w & 1;
  const int mrow = blockIdx.x * 128;
  const int ncol = blockIdx.y * 128;

  f32x4 acc[4][4];
  #pragma unroll
  for (int m = 0; m < 4; ++m)
    #pragma unroll
    for (int n = 0; n < 4; ++n) { f32x4 z = {0.f,0.f,0.f,0.f}; acc[m][n] = z; }

  for (int k0 = 0; k0 < 1024; k0 += 64) {
    #pragma unroll
    for (int i = 0; i < 4; ++i) {
      int ci = i*256 + t;          // 0..1023 16B-chunks
      int r = ci >> 3;
      int slot = ci & 7;
      int c = slot ^ (r & 7);      // logical k-chunk stored at this slot
      gload16b(A + (size_t)(mrow + r)*1024 + k0 + c*8, lsa + ci*8);
      gload16b(Bw + (size_t)(ncol + r)*1024 + k0 + c*8, lsb + ci*8);
    }
    __syncthreads();
    #pragma unroll
    for (int kk = 0; kk < 64; kk += 32) {
      s16x8 bf[4];
      #pragma unroll
      for (int n = 0; n < 4; ++n) bf[n] = fragload16(lsb, wn*64 + n*16, kk, l);
      #pragma unroll
      for (int m = 0; m < 4; ++m) {
        s16x8 af = fragload16(lsa, wm*64 + m*16, kk, l);
        #pragma unroll
        for (int n = 0; n < 4; ++n)
          acc[m][n] = __builtin_amdgcn_mfma_f32_16x16x32_bf16(af, bf[n], acc[m][n], 0, 0, 0);
      }
    }
    __syncthreads();
  }

  const int kq = l >> 4, lc = l & 15;
  float vv[4];
  #pragma unroll
  for (int n = 0; n < 4; ++n) vv[n] = vb[ncol + wn*64 + n*16 + lc];
  #pragma unroll
  for (int m = 0; m < 4; ++m) {
    #pragma unroll
    for (int j = 0; j < 4; ++j) {
      int r = mrow + wm*64 + m*16 + kq*4 + j;
      int b = r / SS;
      const float* qb = qv + b*HH + ncol + wn*64 + lc;
      float ps = 0.f;
      #pragma unroll
      for (int n = 0; n < 4; ++n) ps += vv[n]*tanhfast(acc[m][n][j] + qb[n*16]);
      #pragma unroll
      for (int o = 1; o < 16; o <<= 1) ps += __shfl_xor(ps, o);
      if (lc == 0) dst[(blockIdx.y*2 + wn)*MTOT + r] = ps;
    }
  }
}

// ---------- MFMA GEMM (f32 inputs staged, cvt in fragload) ----------
// SCORE=true : fused epilogue  partial_score[r] += sum_h v[h]*tanh(P[r,h]+q[b,h])
// SCORE=false: dst[r*Ntot+c] = acc + vb[c]
template<int BM, int MREP, bool SCORE>
__global__ __launch_bounds__(256) void mfma_gemm(
    const float* __restrict__ A, const float* __restrict__ Bw, int K,
    const float* __restrict__ qv, const float* __restrict__ vb,
    float* __restrict__ dst, int Ntot)
{
  __shared__ __align__(16) float lsa[BM*32];
  __shared__ __align__(16) float lsb[128*32];
  const int t = threadIdx.x;
  const int l = t & 63;
  const int w = t >> 6;
  const int wm = w >> 1, wn = w & 1;
  const int mrow = blockIdx.x * BM;
  const int ncol = blockIdx.y * 128;

  f32x4 acc[MREP][4];
  #pragma unroll
  for (int m = 0; m < MREP; ++m)
    #pragma unroll
    for (int n = 0; n < 4; ++n) { f32x4 z = {0.f,0.f,0.f,0.f}; acc[m][n] = z; }

  for (int k0 = 0; k0 < K; k0 += 32) {
    #pragma unroll
    for (int i = 0; i < BM*8/256; ++i) {
      int idx = i*256 + t;
      int r = idx >> 3, c = idx & 7;
      int cg = c ^ (r & 7);
      gload16(A + (size_t)(mrow + r)*K + k0 + cg*4, lsa + idx*4);
    }
    #pragma unroll
    for (int i = 0; i < 4; ++i) {
      int idx = i*256 + t;
      int r = idx >> 3, c = idx & 7;
      int cg = c ^ (r & 7);
      gload16(Bw + (size_t)(ncol + r)*K + k0 + cg*4, lsb + idx*4);
    }
    __syncthreads();
    s16x8 bf[4];
    #pragma unroll
    for (int n = 0; n < 4; ++n) bf[n] = fragload(lsb, wn*64 + n*16, l);
    #pragma unroll
    for (int m = 0; m < MREP; ++m) {
      s16x8 af = fragload(lsa, wm*(MREP*16) + m*16, l);
      #pragma unroll
      for (int n = 0; n < 4; ++n)
        acc[m][n] = __builtin_amdgcn_mfma_f32_16x16x32_bf16(af, bf[n], acc[m][n], 0, 0, 0);
    }
    __syncthreads();
  }

  const int kq = l >> 4, lc = l & 15;
  if (SCORE) {
    float vv[4];
    #pragma unroll
    for (int n = 0; n < 4; ++n) vv[n] = vb[ncol + wn*64 + n*16 + lc];
    #pragma unroll
    for (int m = 0; m < MREP; ++m) {
      #pragma unroll
      for (int j = 0; j < 4; ++j) {
        int r = mrow + wm*(MREP*16) + m*16 + kq*4 + j;
        int b = r / SS;
        const float* qb = qv + b*HH + ncol + wn*64 + lc;
        float ps = 0.f;
        #pragma unroll
        for (int n = 0; n < 4; ++n) ps += vv[n]*tanhfast(acc[m][n][j] + qb[n*16]);
        #pragma unroll
        for (int o = 1; o < 16; o <<= 1) ps += __shfl_xor(ps, o);
        if (lc == 0) dst[(blockIdx.y*2 + wn)*MTOT + r] = ps;
      }
    }
  } else {
    #pragma unroll
    for (int m = 0; m < MREP; ++m)
      #pragma unroll
      for (int j = 0; j < 4; ++j) {
        int r = mrow + wm*(MREP*16) + m*16 + kq*4 + j;
        #pragma unroll
        for (int n = 0; n < 4; ++n) {
          int c = ncol + wn*64 + n*16 + lc;
          dst[(size_t)r*Ntot + c] = acc[m][n][j] + vb[c];
        }
      }
  }
}

// ---------- small f32 GEMM (M=64), K-split partials ----------
__global__ __launch_bounds__(256) void sgemm_part(
    const float* __restrict__ A0, const float* __restrict__ A1,
    const float* __restrict__ W0, const float* __restrict__ W1,
    float* __restrict__ P0, float* __restrict__ P1,
    int K, int N, int KSEG)
{
  const float* A = blockIdx.z ? A1 : A0;
  const float* W = blockIdx.z ? W1 : W0;
  float*       P = blockIdx.z ? P1 : P0;
  __shared__ float sa[64][65];
  __shared__ float sw[64][65];
  int t = threadIdx.x;
  int bg = (t & 15) * 4, cg = (t >> 4) * 4;
  int c0 = blockIdx.x * 64;
  float acc[4][4] = {};
  int kbeg = blockIdx.y * KSEG;
  for (int kc = 0; kc < KSEG; kc += 64) {
    int kk = kbeg + kc;
    for (int i = t; i < 4096; i += 256) {
      int r = i >> 6, k = i & 63;
      sa[k][r] = A[(size_t)r*K + kk + k];
      sw[r][k] = W[(size_t)(c0 + r)*K + kk + k];
    }
    __syncthreads();
    #pragma unroll 8
    for (int k = 0; k < 64; ++k) {
      float av[4], wv[4];
      #pragma unroll
      for (int i = 0; i < 4; ++i) { av[i] = sa[k][bg+i]; wv[i] = sw[cg+i][k]; }
      #pragma unroll
      for (int i = 0; i < 4; ++i)
        #pragma unroll
        for (int j = 0; j < 4; ++j) acc[i][j] += av[i]*wv[j];
    }
    __syncthreads();
  }
  size_t pbase = (size_t)blockIdx.y * 64 * N;
  #pragma unroll
  for (int i = 0; i < 4; ++i)
    #pragma unroll
    for (int j = 0; j < 4; ++j)
      P[pbase + (size_t)(bg+i)*N + c0 + cg + j] = acc[i][j];
}

// ---------- combine 8 K-split partials + biases ----------
__global__ void combine8(const float* __restrict__ P, const float* __restrict__ b1,
                         const float* __restrict__ b2, float* __restrict__ dstv,
                         int N, int total)
{
  int i = blockIdx.x*256 + threadIdx.x;
  if (i >= total) return;
  float a = 0.f;
  #pragma unroll
  for (int s = 0; s < 8; ++s) a += P[(size_t)s*total + i];
  int c = i % N;
  if (b1) a += b1[c];
  if (b2) a += b2[c];
  dstv[i] = a;
}

// ---------- GRU gate combine ----------
__global__ void gru_gate(const float* __restrict__ GI, const float* __restrict__ GH,
                         const float* __restrict__ b_ih, const float* __restrict__ b_hh,
                         const float* __restrict__ hprev, float* __restrict__ hid,
                         float* __restrict__ concat)
{
  int i = blockIdx.x*256 + threadIdx.x;
  int b = i >> 9, h = i & 511;
  float ir=0, iz=0, inn=0, hr=0, hz=0, hn=0;
  #pragma unroll
  for (int s = 0; s < 8; ++s) {
    const float* gi = GI + (size_t)s*(64*1536) + b*1536;
    const float* gh = GH + (size_t)s*(64*1536) + b*1536;
    ir += gi[h];      iz += gi[512+h];  inn += gi[1024+h];
    hr += gh[h];      hz += gh[512+h];  hn  += gh[1024+h];
  }
  ir += b_ih[h]; iz += b_ih[512+h]; inn += b_ih[1024+h];
  hr += b_hh[h]; hz += b_hh[512+h]; hn  += b_hh[1024+h];
  float r = sigm(ir + hr), z = sigm(iz + hz);
  float n = tanhfast(inn + r*hn);
  float hv = (1.f - z)*n + z*hprev[i];
  hid[i] = hv;
  concat[b*1536 + h] = hv;
}

// ---------- masked softmax over S ----------
__global__ void softmax_s(const float* __restrict__ part, const void* __restrict__ mask,
                          const int* __restrict__ flag, float* __restrict__ attn)
{
  __shared__ float red[4];
  int b = blockIdx.x, t = threadIdx.x;
  bool isbyte = (*flag != 0);
  float sc0, sc1 = -INFINITY;
  {
    float v = 0.f;
    #pragma unroll
    for (int p = 0; p < 8; ++p) v += part[p*MTOT + b*SS + t];
    bool mv = isbyte ? (((const unsigned char*)mask)[b*SS + t] != 0)
                     : (((const int*)mask)[b*SS + t] != 0);
    sc0 = mv ? v : -INFINITY;
  }
  int s1 = t + 256;
  if (s1 < SS) {
    float v = 0.f;
    #pragma unroll
    for (int p = 0; p < 8; ++p) v += part[p*MTOT + b*SS + s1];
    bool mv = isbyte ? (((const unsigned char*)mask)[b*SS + s1] != 0)
                     : (((const int*)mask)[b*SS + s1] != 0);
    sc1 = mv ? v : -INFINITY;
  }
  float mx = blkmax(fmaxf(sc0, sc1), red, t);
  float e0 = __expf(sc0 - mx), e1 = __expf(sc1 - mx);
  float sum = blksum(e0 + e1, red, t);
  float inv = 1.f / sum;
  attn[b*SS + t] = e0 * inv;
  if (s1 < SS) attn[b*SS + s1] = e1 * inv;
}

// ---------- context = attn @ enc (bf16 enc copy; 2 cols per thread) ----------
__global__ void ctx_kernel_bf16(const float* __restrict__ attn, const unsigned int* __restrict__ enc16,
                                float* __restrict__ ctx, float* __restrict__ concat)
{
  int b = blockIdx.x;
  int d0 = blockIdx.y*512 + threadIdx.x*2;
  const float* a = attn + b*SS;
  const unsigned int* e = enc16 + ((size_t)b*SS*1024 + d0) / 2;
  float s0=0, s1=0, s2=0, s3=0;
  for (int s = 0; s < SS; s += 2) {
    unsigned int u0 = e[(size_t)s*512];
    unsigned int u1 = e[(size_t)(s+1)*512];
    float a0 = a[s], a1 = a[s+1];
    s0 += a0 * __uint_as_float(u0 << 16);
    s1 += a0 * __uint_as_float(u0 & 0xffff0000u);
    s2 += a1 * __uint_as_float(u1 << 16);
    s3 += a1 * __uint_as_float(u1 & 0xffff0000u);
  }
  float lo = s0 + s2, hi = s1 + s3;
  ctx[b*1024 + d0]     = lo;
  ctx[b*1024 + d0 + 1] = hi;
  concat[b*1536 + 512 + d0]     = lo;
  concat[b*1536 + 512 + d0 + 1] = hi;
}

// ---------- context, f32 fallback ----------
__global__ void ctx_kernel(const float* __restrict__ attn, const float* __restrict__ enc,
                           float* __restrict__ ctx, float* __restrict__ concat)
{
  int b = blockIdx.x, dc = blockIdx.y;
  int d = dc*256 + threadIdx.x;
  const float* a = attn + b*SS;
  const float* e = enc + (size_t)b*SS*1024 + d;
  float s0=0,s1=0,s2=0,s3=0;
  for (int s = 0; s < SS; s += 4) {
    s0 += a[s  ]*e[(size_t)(s  )*1024];
    s1 += a[s+1]*e[(size_t)(s+1)*1024];
    s2 += a[s+2]*e[(size_t)(s+2)*1024];
    s3 += a[s+3]*e[(size_t)(s+3)*1024];
  }
  float tot = (s0+s1)+(s2+s3);
  ctx[b*1024 + d] = tot;
  concat[b*1536 + 512 + d] = tot;
}

// ---------- vocab softmax (in-place) ----------
__global__ void vsoftmax(float* __restrict__ logits)
{
  __shared__ float red[4];
  int b = blockIdx.x, t = threadIdx.x;
  float* p = logits + (size_t)b * VVOC;
  float mx = -1e30f;
  for (int i = t; i < VVOC; i += 256) mx = fmaxf(mx, p[i]);
  mx = blkmax(mx, red, t);
  float sm = 0.f;
  for (int i = t; i < VVOC; i += 256) sm += __expf(p[i] - mx);
  sm = blksum(sm, red, t);
  float inv = 1.f / sm;
  for (int i = t; i < VVOC; i += 256) p[i] = __expf(p[i] - mx) * inv;
}

// ---------- launch ----------
extern "C" void kernel_launch(void* const* d_in, const int* in_sizes, int n_in,
                              void* d_out, int out_size, void* d_ws, size_t ws_size,
                              hipStream_t stream) {
  (void)in_sizes; (void)n_in; (void)out_size;
  const float* x      = (const float*)d_in[0];
  const float* hprev  = (const float*)d_in[1];
  const float* enc    = (const float*)d_in[2];
  const void*  mask   = d_in[3];
  const float* w_ih   = (const float*)d_in[4];
  const float* w_hh   = (const float*)d_in[5];
  const float* b_ih   = (const float*)d_in[6];
  const float* b_hh   = (const float*)d_in[7];
  const float* Wh_w   = (const float*)d_in[8];
  const float* Wh_b   = (const float*)d_in[9];
  const float* Ws_w   = (const float*)d_in[10];
  const float* Ws_b   = (const float*)d_in[11];
  const float* vatt   = (const float*)d_in[12];
  const float* V_w    = (const float*)d_in[13];
  const float* V_b    = (const float*)d_in[14];
  const float* Vhat_w = (const float*)d_in[15];
  const float* Vhat_b = (const float*)d_in[16];

  float* out   = (float*)d_out;
  float* vocab = out;                    // [64,32000]
  float* attn  = out + 2048000;          // [64,400]
  float* ctx   = out + 2073600;          // [64,1024]
  float* hid   = out + 2139136;          // [64,512]

  float* WS = (float*)d_ws;
  int*   flag   = (int*)d_ws;
  float* GI     = WS + 16;               // 8*64*1536
  float* GH     = GI + 786432;
  float* CONCAT = GH + 786432;           // 64*1536
  float* QP     = CONCAT + 98304;        // 8*64*512
  float* Q      = QP + 262144;           // 64*512
  float* OUTP   = Q + 32768;             // 8*64*512
  float* OUT    = OUTP + 262144;         // 64*512
  float* PART   = OUT + 32768;           // 8*25600
  float* ENDF   = PART + 204800;         // end of f32 region
  // bf16 region (16B aligned)
  size_t f32_bytes = (size_t)((char*)ENDF - (char*)d_ws);
  f32_bytes = (f32_bytes + 15) & ~(size_t)15;
  short* ENC16 = (short*)((char*)d_ws + f32_bytes);       // 25600*1024 bf16
  short* WH16  = ENC16 + (size_t)25600*1024;              // 512*1024 bf16
  size_t need = f32_bytes + ((size_t)25600*1024 + 512*1024)*2;
  bool use_bf16 = (ws_size >= need);

  detect_mask<<<1, 256, 0, stream>>>((const unsigned int*)mask, (BB*SS)/4, flag);

  // GRU gate GEMMs
  sgemm_part<<<dim3(1536/64, 8, 2), 256, 0, stream>>>(x, hprev, w_ih, w_hh, GI, GH, 512, 1536, 64);
  gru_gate<<<dim3(128), 256, 0, stream>>>(GI, GH, b_ih, b_hh, hprev, hid, CONCAT);

  // q = hidden@Ws^T + Ws_b + Wh_b
  sgemm_part<<<dim3(8, 8, 1), 256, 0, stream>>>(hid, hid, Ws_w, Ws_w, QP, QP, 512, 512, 64);
  combine8<<<dim3(128), 256, 0, stream>>>(QP, Ws_b, Wh_b, Q, 512, 32768);

  if (use_bf16) {
    // pre-convert enc + Wh_w to bf16 (independent of GRU chain; serialized on stream anyway)
    cvt_bf16<<<dim3(2048), 256, 0, stream>>>(enc, ENC16, 25600*1024/8);
    cvt_bf16<<<dim3(256), 256, 0, stream>>>(Wh_w, WH16, 512*1024/8);
    score_gemm_bf16<<<dim3(200, 4), 256, 0, stream>>>(
        (const __hip_bfloat16*)ENC16, (const __hip_bfloat16*)WH16, Q, vatt, PART);
    softmax_s<<<dim3(64), 256, 0, stream>>>(PART, mask, flag, attn);
    ctx_kernel_bf16<<<dim3(64, 2), 256, 0, stream>>>(attn, (const unsigned int*)ENC16, ctx, CONCAT);
  } else {
    mfma_gemm<128, 4, true><<<dim3(200, 4), 256, 0, stream>>>(enc, Wh_w, 1024, Q, vatt, PART, 0);
    softmax_s<<<dim3(64), 256, 0, stream>>>(PART, mask, flag, attn);
    ctx_kernel<<<dim3(64, 4), 256, 0, stream>>>(attn, enc, ctx, CONCAT);
  }

  // out = concat@V_w^T + V_b
  sgemm_part<<<dim3(8, 8, 1), 256, 0, stream>>>(CONCAT, CONCAT, V_w, V_w, OUTP, OUTP, 1536, 512, 192);
  combine8<<<dim3(128), 256, 0, stream>>>(OUTP, V_b, nullptr, OUT, 512, 32768);

  // logits = out@Vhat^T + Vhat_b, then in-place softmax
  mfma_gemm<64, 2, false><<<dim3(1, 250), 256, 0, stream>>>(OUT, Vhat_w, 512, nullptr, Vhat_b, vocab, VVOC);
  vsoftmax<<<dim3(64), 256, 0, stream>>>(vocab);
}

// Round 3
// 243.073 us; speedup vs baseline: 1.0146x; 1.0146x over previous
//
#include <hip/hip_runtime.h>
#include <hip/hip_bf16.h>
#include <stdint.h>

#define DI __device__ __forceinline__

using f32x4 = __attribute__((ext_vector_type(4))) float;
using s16x8 = __attribute__((ext_vector_type(8))) short;

#define BB 64
#define SS 400
#define HH 512
#define VVOC 32000
#define MTOT (BB*SS)   // 25600

// ---------- helpers ----------
DI short bf16r(float f){
  __hip_bfloat16 h = __float2bfloat16(f);
  union { __hip_bfloat16 h; short s; } u; u.h = h; return u.s;
}
DI float sigm(float x){ return 1.f/(1.f + __expf(-x)); }
DI float tanhfast(float x){ x = fminf(x, 12.f); float e = __expf(2.f*x); return (e-1.f)/(e+1.f); }

DI void gload16b(const __hip_bfloat16* g, short* l){
  __builtin_amdgcn_global_load_lds(
      (const __attribute__((address_space(1))) __hip_bfloat16*)g,
      (__attribute__((address_space(3))) short*)l, 16, 0, 0);
}

DI float blkmax(float v, float* red, int t){
  #pragma unroll
  for (int o = 32; o; o >>= 1) v = fmaxf(v, __shfl_xor(v, o));
  if ((t & 63) == 0) red[t >> 6] = v;
  __syncthreads();
  v = fmaxf(fmaxf(red[0], red[1]), fmaxf(red[2], red[3]));
  __syncthreads();
  return v;
}
DI float blksum(float v, float* red, int t){
  #pragma unroll
  for (int o = 32; o; o >>= 1) v += __shfl_xor(v, o);
  if ((t & 63) == 0) red[t >> 6] = v;
  __syncthreads();
  v = red[0] + red[1] + red[2] + red[3];
  __syncthreads();
  return v;
}

DI s16x8 cvt8(const float* src){
  f32x4 a = ((const f32x4*)src)[0];
  f32x4 b = ((const f32x4*)src)[1];
  s16x8 o;
  o[0]=bf16r(a[0]); o[1]=bf16r(a[1]); o[2]=bf16r(a[2]); o[3]=bf16r(a[3]);
  o[4]=bf16r(b[0]); o[5]=bf16r(b[1]); o[6]=bf16r(b[2]); o[7]=bf16r(b[3]);
  return o;
}

// bf16 LDS tile: row stride 64 shorts (128B), 8 chunks of 16B, slot = chunk ^ (row&7)
DI s16x8 fragload16(const short* tile, int rbase, int kk, int l){
  int r = rbase + (l & 15);
  int c = (kk >> 3) + (l >> 4);
  int slot = c ^ (r & 7);
  return *(const s16x8*)(tile + r*64 + slot*8);
}

// ---------- fused cvt (enc, Wh) + mask dtype detect ----------
// grid: [0,1600) enc cvt, [1600,1856) Wh cvt, [1856,1864) mask detect
__global__ __launch_bounds__(256) void cvt_all(
    const float* __restrict__ enc, const float* __restrict__ wh,
    short* __restrict__ enc16, short* __restrict__ wh16,
    const unsigned int* __restrict__ mask, int mwords, int* __restrict__ flags)
{
  int b = blockIdx.x, t = threadIdx.x;
  if (b < 1600) {
    int i = b*256 + t;  // stride 409600, 8 items of 8 f32
    #pragma unroll
    for (int k = 0; k < 8; ++k) {
      int idx = i + k*409600;
      ((s16x8*)enc16)[idx] = cvt8(enc + (size_t)idx*8);
    }
  } else if (b < 1856) {
    int i = (b-1600)*256 + t;   // 65536 items
    ((s16x8*)wh16)[i] = cvt8(wh + (size_t)i*8);
  } else {
    __shared__ int f;
    if (t == 0) f = 0;
    __syncthreads();
    int loc = 0;
    for (int i = (b-1856)*256 + t; i < mwords; i += 8*256) loc |= (mask[i] > 1u) ? 1 : 0;
    if (loc) atomicOr(&f, 1);
    __syncthreads();
    if (t == 0) flags[b-1856] = f;
  }
}

// ---------- bf16 score GEMM + fused tanh-dot epilogue, XCD-chunked swizzle ----------
__global__ __launch_bounds__(256) void score_gemm_bf16(
    const __hip_bfloat16* __restrict__ A, const __hip_bfloat16* __restrict__ Bw,
    const float* __restrict__ qv, const float* __restrict__ vb, float* __restrict__ dst)
{
  __shared__ __align__(16) short lsa[128*64];
  __shared__ __align__(16) short lsb[128*64];
  const int t = threadIdx.x;
  const int l = t & 63;
  const int w = t >> 6;
  const int wm = w >> 1, wn = w & 1;
  // 800 blocks; phys round-robins XCDs -> logical chunked per XCD; same-A col-blocks adjacent
  const int phys = blockIdx.x;
  const int logical = (phys & 7)*100 + (phys >> 3);
  const int mrow = (logical >> 2) * 128;
  const int colb = logical & 3;
  const int ncol = colb * 128;

  f32x4 acc[4][4];
  #pragma unroll
  for (int m = 0; m < 4; ++m)
    #pragma unroll
    for (int n = 0; n < 4; ++n) { f32x4 z = {0.f,0.f,0.f,0.f}; acc[m][n] = z; }

  for (int k0 = 0; k0 < 1024; k0 += 64) {
    #pragma unroll
    for (int i = 0; i < 4; ++i) {
      int ci = i*256 + t;          // 0..1023 16B-chunks
      int r = ci >> 3;
      int slot = ci & 7;
      int c = slot ^ (r & 7);      // pre-swizzled global source, linear LDS dest
      gload16b(A + (size_t)(mrow + r)*1024 + k0 + c*8, lsa + ci*8);
      gload16b(Bw + (size_t)(ncol + r)*1024 + k0 + c*8, lsb + ci*8);
    }
    __syncthreads();
    #pragma unroll
    for (int kk = 0; kk < 64; kk += 32) {
      s16x8 bf[4];
      #pragma unroll
      for (int n = 0; n < 4; ++n) bf[n] = fragload16(lsb, wn*64 + n*16, kk, l);
      #pragma unroll
      for (int m = 0; m < 4; ++m) {
        s16x8 af = fragload16(lsa, wm*64 + m*16, kk, l);
        #pragma unroll
        for (int n = 0; n < 4; ++n)
          acc[m][n] = __builtin_amdgcn_mfma_f32_16x16x32_bf16(af, bf[n], acc[m][n], 0, 0, 0);
      }
    }
    __syncthreads();
  }

  const int kq = l >> 4, lc = l & 15;
  float vv[4];
  #pragma unroll
  for (int n = 0; n < 4; ++n) vv[n] = vb[ncol + wn*64 + n*16 + lc];
  #pragma unroll
  for (int m = 0; m < 4; ++m) {
    #pragma unroll
    for (int j = 0; j < 4; ++j) {
      int r = mrow + wm*64 + m*16 + kq*4 + j;
      int b = r / SS;
      const float* qb = qv + b*HH + ncol + wn*64 + lc;
      float ps = 0.f;
      #pragma unroll
      for (int n = 0; n < 4; ++n) ps += vv[n]*tanhfast(acc[m][n][j] + qb[n*16]);
      #pragma unroll
      for (int o = 1; o < 16; o <<= 1) ps += __shfl_xor(ps, o);
      if (lc == 0) dst[(colb*2 + wn)*MTOT + r] = ps;
    }
  }
}

// ---------- vocab GEMM: logits = OUT[64,512] @ Vhat[32000,512]^T + Vb ----------
// f32 sources reg-staged -> bf16 LDS (converted once per element); also emits
// per-block per-batch-row max & sum-exp partials for the softmax.
__global__ __launch_bounds__(256) void vocab_gemm(
    const float* __restrict__ OUTm, const float* __restrict__ Vhat,
    const float* __restrict__ Vb, float* __restrict__ logits,
    float* __restrict__ MAXP, float* __restrict__ SUMP)
{
  __shared__ __align__(16) short lsa[64*64];   // OUT tile  [64 batch][64 k]
  __shared__ __align__(16) short lsb[64*64];   // Vhat tile [64 voc][64 k]
  __shared__ float red[64][8];
  const int t = threadIdx.x, l = t & 63, w = t >> 6;
  const int vrow0 = blockIdx.x * 64;

  f32x4 acc[4];
  #pragma unroll
  for (int m = 0; m < 4; ++m) { f32x4 z = {0.f,0.f,0.f,0.f}; acc[m] = z; }

  for (int k0 = 0; k0 < 512; k0 += 64) {
    #pragma unroll
    for (int q = 0; q < 2; ++q) {            // A tile: 512 items of 8 f32
      int it = q*256 + t;
      int r = it >> 3, c = it & 7;
      s16x8 o = cvt8(OUTm + (size_t)r*512 + k0 + c*8);
      *(s16x8*)(lsa + r*64 + ((c ^ (r & 7)) << 3)) = o;
    }
    #pragma unroll
    for (int q = 0; q < 2; ++q) {            // B tile: 512 items
      int it = q*256 + t;
      int r = it >> 3, c = it & 7;
      s16x8 o = cvt8(Vhat + (size_t)(vrow0 + r)*512 + k0 + c*8);
      *(s16x8*)(lsb + r*64 + ((c ^ (r & 7)) << 3)) = o;
    }
    __syncthreads();
    #pragma unroll
    for (int kk = 0; kk < 64; kk += 32) {
      s16x8 bf = fragload16(lsb, w*16, kk, l);
      #pragma unroll
      for (int m = 0; m < 4; ++m) {
        s16x8 af = fragload16(lsa, m*16, kk, l);
        acc[m] = __builtin_amdgcn_mfma_f32_16x16x32_bf16(af, bf, acc[m], 0, 0, 0);
      }
    }
    __syncthreads();
  }

  const int kq = l >> 4, lc = l & 15;
  const int voc = vrow0 + w*16 + lc;
  const float bias = Vb[voc];
  #pragma unroll
  for (int m = 0; m < 4; ++m)
    #pragma unroll
    for (int j = 0; j < 4; ++j) {
      acc[m][j] += bias;
      int brow = m*16 + kq*4 + j;
      logits[(size_t)brow*VVOC + voc] = acc[m][j];
    }
  // per-batch-row max over this wave's 16 voc cols
  #pragma unroll
  for (int m = 0; m < 4; ++m)
    #pragma unroll
    for (int j = 0; j < 4; ++j) {
      float v = acc[m][j];
      #pragma unroll
      for (int o = 1; o < 16; o <<= 1) v = fmaxf(v, __shfl_xor(v, o));
      if (lc == 0) red[m*16 + kq*4 + j][w] = v;
    }
  __syncthreads();
  float gmax[4][4];
  #pragma unroll
  for (int m = 0; m < 4; ++m)
    #pragma unroll
    for (int j = 0; j < 4; ++j) {
      int row = m*16 + kq*4 + j;
      gmax[m][j] = fmaxf(fmaxf(red[row][0], red[row][1]), fmaxf(red[row][2], red[row][3]));
    }
  __syncthreads();
  #pragma unroll
  for (int m = 0; m < 4; ++m)
    #pragma unroll
    for (int j = 0; j < 4; ++j) {
      float s = __expf(acc[m][j] - gmax[m][j]);
      #pragma unroll
      for (int o = 1; o < 16; o <<= 1) s += __shfl_xor(s, o);
      if (lc == 0) red[m*16 + kq*4 + j][4 + w] = s;
    }
  __syncthreads();
  if (t < 64) {
    float M = fmaxf(fmaxf(red[t][0], red[t][1]), fmaxf(red[t][2], red[t][3]));
    float S = red[t][4] + red[t][5] + red[t][6] + red[t][7];
    MAXP[blockIdx.x*64 + t] = M;
    SUMP[blockIdx.x*64 + t] = S;
  }
}

// ---------- vocab softmax normalize (+ ctx partial combine on q==0) ----------
__global__ __launch_bounds__(256) void vnorm(
    const float* __restrict__ MAXP, const float* __restrict__ SUMP,
    float* __restrict__ logits, const float* __restrict__ CTXP, float* __restrict__ ctx)
{
  __shared__ float red[4];
  int b = blockIdx.x, q = blockIdx.y, t = threadIdx.x;
  float m = -INFINITY;
  for (int i = t; i < 500; i += 256) m = fmaxf(m, MAXP[i*64 + b]);
  m = blkmax(m, red, t);
  float z = 0.f;
  for (int i = t; i < 500; i += 256) z += SUMP[i*64 + b] * __expf(MAXP[i*64 + b] - m);
  z = blksum(z, red, t);
  float inv = 1.f / z;
  f32x4* p = (f32x4*)(logits + (size_t)b*VVOC + q*8000);
  for (int i = t; i < 2000; i += 256) {
    f32x4 v = p[i];
    #pragma unroll
    for (int c = 0; c < 4; ++c) v[c] = __expf(v[c] - m) * inv;
    p[i] = v;
  }
  if (q == 0) {
    for (int d = t; d < 1024; d += 256) {
      float s = CTXP[b*1024 + d] + CTXP[65536 + b*1024 + d]
              + CTXP[131072 + b*1024 + d] + CTXP[196608 + b*1024 + d];
      ctx[b*1024 + d] = s;
    }
  }
}

// ---------- small f32 GEMM (M=64), K-split partials ----------
__global__ __launch_bounds__(256) void sgemm_part(
    const float* __restrict__ A0, const float* __restrict__ A1,
    const float* __restrict__ W0, const float* __restrict__ W1,
    float* __restrict__ P0, float* __restrict__ P1,
    int K, int N, int KSEG)
{
  const float* A = blockIdx.z ? A1 : A0;
  const float* W = blockIdx.z ? W1 : W0;
  float*       P = blockIdx.z ? P1 : P0;
  __shared__ float sa[64][65];
  __shared__ float sw[64][65];
  int t = threadIdx.x;
  int bg = (t & 15) * 4, cg = (t >> 4) * 4;
  int c0 = blockIdx.x * 64;
  float acc[4][4] = {};
  int kbeg = blockIdx.y * KSEG;
  for (int kc = 0; kc < KSEG; kc += 64) {
    int kk = kbeg + kc;
    for (int i = t; i < 4096; i += 256) {
      int r = i >> 6, k = i & 63;
      sa[k][r] = A[(size_t)r*K + kk + k];
      sw[r][k] = W[(size_t)(c0 + r)*K + kk + k];
    }
    __syncthreads();
    #pragma unroll 8
    for (int k = 0; k < 64; ++k) {
      float av[4], wv[4];
      #pragma unroll
      for (int i = 0; i < 4; ++i) { av[i] = sa[k][bg+i]; wv[i] = sw[cg+i][k]; }
      #pragma unroll
      for (int i = 0; i < 4; ++i)
        #pragma unroll
        for (int j = 0; j < 4; ++j) acc[i][j] += av[i]*wv[j];
    }
    __syncthreads();
  }
  size_t pbase = (size_t)blockIdx.y * 64 * N;
  #pragma unroll
  for (int i = 0; i < 4; ++i)
    #pragma unroll
    for (int j = 0; j < 4; ++j)
      P[pbase + (size_t)(bg+i)*N + c0 + cg + j] = acc[i][j];
}

// ---------- out-projection GEMM: A = [hid | sum4(CTXP)], K=1536, 4-way K-split ----------
__global__ __launch_bounds__(256) void sgemm_out(
    const float* __restrict__ hid, const float* __restrict__ CTXP,
    const float* __restrict__ W, float* __restrict__ P)
{
  __shared__ float sa[64][65];
  __shared__ float sw[64][65];
  int t = threadIdx.x;
  int bg = (t & 15) * 4, cg = (t >> 4) * 4;
  int c0 = blockIdx.x * 64;
  int kbeg = blockIdx.y * 384;
  float acc[4][4] = {};
  for (int kc = 0; kc < 384; kc += 64) {
    int kk = kbeg + kc;
    for (int i = t; i < 4096; i += 256) {
      int r = i >> 6, k = i & 63;
      int kg = kk + k;
      float av;
      if (kg < 512) av = hid[r*512 + kg];
      else {
        int d = kg - 512;
        av = CTXP[r*1024 + d] + CTXP[65536 + r*1024 + d]
           + CTXP[131072 + r*1024 + d] + CTXP[196608 + r*1024 + d];
      }
      sa[k][r] = av;
      sw[r][k] = W[(size_t)(c0 + r)*1536 + kg];
    }
    __syncthreads();
    #pragma unroll 8
    for (int k = 0; k < 64; ++k) {
      float av[4], wv[4];
      #pragma unroll
      for (int i = 0; i < 4; ++i) { av[i] = sa[k][bg+i]; wv[i] = sw[cg+i][k]; }
      #pragma unroll
      for (int i = 0; i < 4; ++i)
        #pragma unroll
        for (int j = 0; j < 4; ++j) acc[i][j] += av[i]*wv[j];
    }
    __syncthreads();
  }
  size_t pbase = (size_t)blockIdx.y * 32768;
  #pragma unroll
  for (int i = 0; i < 4; ++i)
    #pragma unroll
    for (int j = 0; j < 4; ++j)
      P[pbase + (size_t)(bg+i)*512 + c0 + cg + j] = acc[i][j];
}

// ---------- combine K-split partials + biases ----------
__global__ void combineN(const float* __restrict__ P, const float* __restrict__ b1,
                         const float* __restrict__ b2, float* __restrict__ dstv,
                         int N, int total, int nseg)
{
  int i = blockIdx.x*256 + threadIdx.x;
  if (i >= total) return;
  float a = 0.f;
  for (int s = 0; s < nseg; ++s) a += P[(size_t)s*total + i];
  int c = i % N;
  if (b1) a += b1[c];
  if (b2) a += b2[c];
  dstv[i] = a;
}

// ---------- GRU gate combine ----------
__global__ void gru_gate(const float* __restrict__ GI, const float* __restrict__ GH,
                         const float* __restrict__ b_ih, const float* __restrict__ b_hh,
                         const float* __restrict__ hprev, float* __restrict__ hid)
{
  int i = blockIdx.x*256 + threadIdx.x;
  int b = i >> 9, h = i & 511;
  float ir=0, iz=0, inn=0, hr=0, hz=0, hn=0;
  #pragma unroll
  for (int s = 0; s < 8; ++s) {
    const float* gi = GI + (size_t)s*(64*1536) + b*1536;
    const float* gh = GH + (size_t)s*(64*1536) + b*1536;
    ir += gi[h];      iz += gi[512+h];  inn += gi[1024+h];
    hr += gh[h];      hz += gh[512+h];  hn  += gh[1024+h];
  }
  ir += b_ih[h]; iz += b_ih[512+h]; inn += b_ih[1024+h];
  hr += b_hh[h]; hz += b_hh[512+h]; hn  += b_hh[1024+h];
  float r = sigm(ir + hr), z = sigm(iz + hz);
  float n = tanhfast(inn + r*hn);
  hid[i] = (1.f - z)*n + z*hprev[i];
}

// ---------- masked softmax over S ----------
__global__ void softmax_s(const float* __restrict__ part, const void* __restrict__ mask,
                          const int* __restrict__ flags, float* __restrict__ attn)
{
  __shared__ float red[4];
  int b = blockIdx.x, t = threadIdx.x;
  bool isbyte = (flags[0]|flags[1]|flags[2]|flags[3]|flags[4]|flags[5]|flags[6]|flags[7]) != 0;
  float sc0, sc1 = -INFINITY;
  {
    float v = 0.f;
    #pragma unroll
    for (int p = 0; p < 8; ++p) v += part[p*MTOT + b*SS + t];
    bool mv = isbyte ? (((const unsigned char*)mask)[b*SS + t] != 0)
                     : (((const int*)mask)[b*SS + t] != 0);
    sc0 = mv ? v : -INFINITY;
  }
  int s1 = t + 256;
  if (s1 < SS) {
    float v = 0.f;
    #pragma unroll
    for (int p = 0; p < 8; ++p) v += part[p*MTOT + b*SS + s1];
    bool mv = isbyte ? (((const unsigned char*)mask)[b*SS + s1] != 0)
                     : (((const int*)mask)[b*SS + s1] != 0);
    sc1 = mv ? v : -INFINITY;
  }
  float mx = blkmax(fmaxf(sc0, sc1), red, t);
  float e0 = __expf(sc0 - mx), e1 = __expf(sc1 - mx);
  float sum = blksum(e0 + e1, red, t);
  float inv = 1.f / sum;
  attn[b*SS + t] = e0 * inv;
  if (s1 < SS) attn[b*SS + s1] = e1 * inv;
}

// ---------- context partials: CTXP[sq][b][1024] over S-quarters ----------
__global__ void ctx_part(const float* __restrict__ attn, const unsigned int* __restrict__ enc16,
                         float* __restrict__ CTXP)
{
  int b = blockIdx.x, dh = blockIdx.y, sq = blockIdx.z;
  int d0 = dh*512 + threadIdx.x*2;
  const float* a = attn + b*SS + sq*100;
  const unsigned int* e = enc16 + (((size_t)b*SS*1024 + (size_t)sq*100*1024 + d0) >> 1);
  float lo = 0.f, hi = 0.f;
  #pragma unroll 4
  for (int s = 0; s < 100; ++s) {
    unsigned int u = e[(size_t)s*512];
    float av = a[s];
    lo += av * __uint_as_float(u << 16);
    hi += av * __uint_as_float(u & 0xffff0000u);
  }
  float* dst = CTXP + (size_t)sq*65536 + b*1024 + d0;
  dst[0] = lo; dst[1] = hi;
}

// ---------- launch ----------
extern "C" void kernel_launch(void* const* d_in, const int* in_sizes, int n_in,
                              void* d_out, int out_size, void* d_ws, size_t ws_size,
                              hipStream_t stream) {
  (void)in_sizes; (void)n_in; (void)out_size; (void)ws_size;
  const float* x      = (const float*)d_in[0];
  const float* hprev  = (const float*)d_in[1];
  const float* enc    = (const float*)d_in[2];
  const void*  mask   = d_in[3];
  const float* w_ih   = (const float*)d_in[4];
  const float* w_hh   = (const float*)d_in[5];
  const float* b_ih   = (const float*)d_in[6];
  const float* b_hh   = (const float*)d_in[7];
  const float* Wh_w   = (const float*)d_in[8];
  const float* Wh_b   = (const float*)d_in[9];
  const float* Ws_w   = (const float*)d_in[10];
  const float* Ws_b   = (const float*)d_in[11];
  const float* vatt   = (const float*)d_in[12];
  const float* V_w    = (const float*)d_in[13];
  const float* V_b    = (const float*)d_in[14];
  const float* Vhat_w = (const float*)d_in[15];
  const float* Vhat_b = (const float*)d_in[16];

  float* out   = (float*)d_out;
  float* vocab = out;                    // [64,32000]
  float* attn  = out + 2048000;          // [64,400]
  float* ctx   = out + 2073600;          // [64,1024]
  float* hid   = out + 2139136;          // [64,512]

  // workspace layout (aliased regions; see timeline in analysis)
  float* WS   = (float*)d_ws;
  int*   FLAGS = (int*)d_ws;            // 16 ints
  float* GI   = WS + 16;                // 786432  | later: PART(204800), MAXP(+204800), SUMP(+236800)
  float* GH   = GI + 786432;            // 786432  | later: CTXP(262144), OUTP(+262144,131072)
  float* QP   = GH + 786432;            // 262144
  float* Q    = QP + 262144;            // 32768
  float* OUT  = Q + 32768;              // 32768
  float* ENDF = OUT + 32768;
  float* PART = GI;
  float* MAXP = GI + 204800;
  float* SUMP = GI + 236800;
  float* CTXP = GH;
  float* OUTP = GH + 262144;
  size_t f32_bytes = ((size_t)((char*)ENDF - (char*)d_ws) + 15) & ~(size_t)15;
  short* ENC16 = (short*)((char*)d_ws + f32_bytes);   // 25600*1024
  short* WH16  = ENC16 + (size_t)25600*1024;          // 512*1024

  // 1. convert enc+Wh to bf16, detect mask dtype
  cvt_all<<<dim3(1864), 256, 0, stream>>>(enc, Wh_w, ENC16, WH16,
                                          (const unsigned int*)mask, 6400, FLAGS);
  // 2-3. GRU
  sgemm_part<<<dim3(24, 8, 2), 256, 0, stream>>>(x, hprev, w_ih, w_hh, GI, GH, 512, 1536, 64);
  gru_gate<<<dim3(128), 256, 0, stream>>>(GI, GH, b_ih, b_hh, hprev, hid);
  // 4-5. q = hid@Ws^T + Ws_b + Wh_b
  sgemm_part<<<dim3(8, 8, 1), 256, 0, stream>>>(hid, hid, Ws_w, Ws_w, QP, QP, 512, 512, 64);
  combineN<<<dim3(128), 256, 0, stream>>>(QP, Ws_b, Wh_b, Q, 512, 32768, 8);
  // 6. fused attention score GEMM (XCD-swizzled)
  score_gemm_bf16<<<dim3(800), 256, 0, stream>>>(
      (const __hip_bfloat16*)ENC16, (const __hip_bfloat16*)WH16, Q, vatt, PART);
  // 7. masked softmax over S
  softmax_s<<<dim3(64), 256, 0, stream>>>(PART, mask, FLAGS, attn);
  // 8. context partials (S split 4)
  ctx_part<<<dim3(64, 2, 4), 256, 0, stream>>>(attn, (const unsigned int*)ENC16, CTXP);
  // 9-10. out = [hid|ctx]@V_w^T + V_b
  sgemm_out<<<dim3(8, 4), 256, 0, stream>>>(hid, CTXP, V_w, OUTP);
  combineN<<<dim3(128), 256, 0, stream>>>(OUTP, V_b, nullptr, OUT, 512, 32768, 4);
  // 11. vocab GEMM + softmax partials
  vocab_gemm<<<dim3(500), 256, 0, stream>>>(OUT, Vhat_w, Vhat_b, vocab, MAXP, SUMP);
  // 12. softmax normalize + ctx combine
  vnorm<<<dim3(64, 4), 256, 0, stream>>>(MAXP, SUMP, vocab, CTXP, ctx);
}

// Round 4
// 157.842 us; speedup vs baseline: 1.5625x; 1.5400x over previous
//
#include <hip/hip_runtime.h>
#include <hip/hip_bf16.h>
#include <stdint.h>

#define DI __device__ __forceinline__

using f32x4 = __attribute__((ext_vector_type(4))) float;
using s16x8 = __attribute__((ext_vector_type(8))) short;

#define BB 64
#define SS 400
#define HH 512
#define VVOC 32000
#define MTOT (BB*SS)   // 25600

// ---------- helpers ----------
DI short bf16r(float f){
  __hip_bfloat16 h = __float2bfloat16(f);
  union { __hip_bfloat16 h; short s; } u; u.h = h; return u.s;
}
DI float sigm(float x){ return 1.f/(1.f + __expf(-x)); }
DI float tanhfast(float x){ x = fminf(x, 12.f); float e = __expf(2.f*x); return (e-1.f)/(e+1.f); }

DI void gload16b(const __hip_bfloat16* g, short* l){
  __builtin_amdgcn_global_load_lds(
      (const __attribute__((address_space(1))) __hip_bfloat16*)g,
      (__attribute__((address_space(3))) short*)l, 16, 0, 0);
}

DI float blkmax(float v, float* red, int t){
  #pragma unroll
  for (int o = 32; o; o >>= 1) v = fmaxf(v, __shfl_xor(v, o));
  if ((t & 63) == 0) red[t >> 6] = v;
  __syncthreads();
  v = fmaxf(fmaxf(red[0], red[1]), fmaxf(red[2], red[3]));
  __syncthreads();
  return v;
}
DI float blksum(float v, float* red, int t){
  #pragma unroll
  for (int o = 32; o; o >>= 1) v += __shfl_xor(v, o);
  if ((t & 63) == 0) red[t >> 6] = v;
  __syncthreads();
  v = red[0] + red[1] + red[2] + red[3];
  __syncthreads();
  return v;
}

DI s16x8 cvt8(const float* src){
  f32x4 a = ((const f32x4*)src)[0];
  f32x4 b = ((const f32x4*)src)[1];
  s16x8 o;
  o[0]=bf16r(a[0]); o[1]=bf16r(a[1]); o[2]=bf16r(a[2]); o[3]=bf16r(a[3]);
  o[4]=bf16r(b[0]); o[5]=bf16r(b[1]); o[6]=bf16r(b[2]); o[7]=bf16r(b[3]);
  return o;
}

// bf16 LDS tile: row stride 64 shorts (128B), 8 chunks of 16B, slot = chunk ^ (row&7)
DI s16x8 fragload16(const short* tile, int rbase, int kk, int l){
  int r = rbase + (l & 15);
  int c = (kk >> 3) + (l >> 4);
  int slot = c ^ (r & 7);
  return *(const s16x8*)(tile + r*64 + slot*8);
}

// ---------- fused cvt (enc, Wh) + mask dtype detect ----------
__global__ __launch_bounds__(256) void cvt_all(
    const float* __restrict__ enc, const float* __restrict__ wh,
    short* __restrict__ enc16, short* __restrict__ wh16,
    const unsigned int* __restrict__ mask, int mwords, int* __restrict__ flags)
{
  int b = blockIdx.x, t = threadIdx.x;
  if (b < 1600) {
    int i = b*256 + t;
    #pragma unroll
    for (int k = 0; k < 8; ++k) {
      int idx = i + k*409600;
      ((s16x8*)enc16)[idx] = cvt8(enc + (size_t)idx*8);
    }
  } else if (b < 1856) {
    int i = (b-1600)*256 + t;
    ((s16x8*)wh16)[i] = cvt8(wh + (size_t)i*8);
  } else {
    __shared__ int f;
    if (t == 0) f = 0;
    __syncthreads();
    int loc = 0;
    for (int i = (b-1856)*256 + t; i < mwords; i += 8*256) loc |= (mask[i] > 1u) ? 1 : 0;
    if (loc) atomicOr(&f, 1);
    __syncthreads();
    if (t == 0) flags[b-1856] = f;
  }
}

// ---------- MFMA small GEMM: P[kseg] = A[64,K](k-chunk) @ W[N,K]^T(k-chunk) ----------
// f32 sources reg-staged -> bf16 LDS. grid: (N/64, K/64, 0|1 source select)
__global__ __launch_bounds__(256) void mfma_small(
    const float* __restrict__ A0, const float* __restrict__ A1,
    const float* __restrict__ W0, const float* __restrict__ W1,
    float* __restrict__ P0, float* __restrict__ P1,
    int K, int N)
{
  const float* A = blockIdx.z ? A1 : A0;
  const float* W = blockIdx.z ? W1 : W0;
  float*       P = blockIdx.z ? P1 : P0;
  __shared__ __align__(16) short lsa[64*64];
  __shared__ __align__(16) short lsb[64*64];
  const int t = threadIdx.x, l = t & 63, w = t >> 6;
  const int c0 = blockIdx.x*64;
  const int kbeg = blockIdx.y*64;

  #pragma unroll
  for (int q = 0; q < 2; ++q) {
    int it = q*256 + t;
    int r = it >> 3, c = it & 7;
    int slot = (c ^ (r & 7)) << 3;
    *(s16x8*)(lsa + r*64 + slot) = cvt8(A + (size_t)r*K + kbeg + c*8);
    *(s16x8*)(lsb + r*64 + slot) = cvt8(W + (size_t)(c0 + r)*K + kbeg + c*8);
  }
  __syncthreads();

  f32x4 acc[4];
  #pragma unroll
  for (int m = 0; m < 4; ++m) { f32x4 z = {0.f,0.f,0.f,0.f}; acc[m] = z; }
  #pragma unroll
  for (int kk = 0; kk < 64; kk += 32) {
    s16x8 bf = fragload16(lsb, w*16, kk, l);
    #pragma unroll
    for (int m = 0; m < 4; ++m) {
      s16x8 af = fragload16(lsa, m*16, kk, l);
      acc[m] = __builtin_amdgcn_mfma_f32_16x16x32_bf16(af, bf, acc[m], 0, 0, 0);
    }
  }
  const int kq = l >> 4, lc = l & 15;
  const int col = c0 + w*16 + lc;
  size_t pbase = (size_t)blockIdx.y * 64 * N;
  #pragma unroll
  for (int m = 0; m < 4; ++m)
    #pragma unroll
    for (int j = 0; j < 4; ++j)
      P[pbase + (size_t)(m*16 + kq*4 + j)*N + col] = acc[m][j];
}

// ---------- bf16 score GEMM + fused tanh-dot epilogue, XCD-chunked swizzle ----------
__global__ __launch_bounds__(256) void score_gemm_bf16(
    const __hip_bfloat16* __restrict__ A, const __hip_bfloat16* __restrict__ Bw,
    const float* __restrict__ qv, const float* __restrict__ vb, float* __restrict__ dst)
{
  __shared__ __align__(16) short lsa[128*64];
  __shared__ __align__(16) short lsb[128*64];
  const int t = threadIdx.x;
  const int l = t & 63;
  const int w = t >> 6;
  const int wm = w >> 1, wn = w & 1;
  const int phys = blockIdx.x;
  const int logical = (phys & 7)*100 + (phys >> 3);
  const int mrow = (logical >> 2) * 128;
  const int colb = logical & 3;
  const int ncol = colb * 128;

  f32x4 acc[4][4];
  #pragma unroll
  for (int m = 0; m < 4; ++m)
    #pragma unroll
    for (int n = 0; n < 4; ++n) { f32x4 z = {0.f,0.f,0.f,0.f}; acc[m][n] = z; }

  for (int k0 = 0; k0 < 1024; k0 += 64) {
    #pragma unroll
    for (int i = 0; i < 4; ++i) {
      int ci = i*256 + t;
      int r = ci >> 3;
      int slot = ci & 7;
      int c = slot ^ (r & 7);
      gload16b(A + (size_t)(mrow + r)*1024 + k0 + c*8, lsa + ci*8);
      gload16b(Bw + (size_t)(ncol + r)*1024 + k0 + c*8, lsb + ci*8);
    }
    __syncthreads();
    #pragma unroll
    for (int kk = 0; kk < 64; kk += 32) {
      s16x8 bf[4];
      #pragma unroll
      for (int n = 0; n < 4; ++n) bf[n] = fragload16(lsb, wn*64 + n*16, kk, l);
      #pragma unroll
      for (int m = 0; m < 4; ++m) {
        s16x8 af = fragload16(lsa, wm*64 + m*16, kk, l);
        #pragma unroll
        for (int n = 0; n < 4; ++n)
          acc[m][n] = __builtin_amdgcn_mfma_f32_16x16x32_bf16(af, bf[n], acc[m][n], 0, 0, 0);
      }
    }
    __syncthreads();
  }

  const int kq = l >> 4, lc = l & 15;
  float vv[4];
  #pragma unroll
  for (int n = 0; n < 4; ++n) vv[n] = vb[ncol + wn*64 + n*16 + lc];
  #pragma unroll
  for (int m = 0; m < 4; ++m) {
    #pragma unroll
    for (int j = 0; j < 4; ++j) {
      int r = mrow + wm*64 + m*16 + kq*4 + j;
      int b = r / SS;
      const float* qb = qv + b*HH + ncol + wn*64 + lc;
      float ps = 0.f;
      #pragma unroll
      for (int n = 0; n < 4; ++n) ps += vv[n]*tanhfast(acc[m][n][j] + qb[n*16]);
      #pragma unroll
      for (int o = 1; o < 16; o <<= 1) ps += __shfl_xor(ps, o);
      if (lc == 0) dst[(colb*2 + wn)*MTOT + r] = ps;
    }
  }
}

// ---------- vocab GEMM: logits = OUT[64,512] @ Vhat[32000,512]^T + Vb ----------
__global__ __launch_bounds__(256) void vocab_gemm(
    const float* __restrict__ OUTm, const float* __restrict__ Vhat,
    const float* __restrict__ Vb, float* __restrict__ logits,
    float* __restrict__ MAXP, float* __restrict__ SUMP)
{
  __shared__ __align__(16) short lsa[64*64];
  __shared__ __align__(16) short lsb[64*64];
  __shared__ float red[64][8];
  const int t = threadIdx.x, l = t & 63, w = t >> 6;
  const int vrow0 = blockIdx.x * 64;

  f32x4 acc[4];
  #pragma unroll
  for (int m = 0; m < 4; ++m) { f32x4 z = {0.f,0.f,0.f,0.f}; acc[m] = z; }

  for (int k0 = 0; k0 < 512; k0 += 64) {
    #pragma unroll
    for (int q = 0; q < 2; ++q) {
      int it = q*256 + t;
      int r = it >> 3, c = it & 7;
      s16x8 o = cvt8(OUTm + (size_t)r*512 + k0 + c*8);
      *(s16x8*)(lsa + r*64 + ((c ^ (r & 7)) << 3)) = o;
    }
    #pragma unroll
    for (int q = 0; q < 2; ++q) {
      int it = q*256 + t;
      int r = it >> 3, c = it & 7;
      s16x8 o = cvt8(Vhat + (size_t)(vrow0 + r)*512 + k0 + c*8);
      *(s16x8*)(lsb + r*64 + ((c ^ (r & 7)) << 3)) = o;
    }
    __syncthreads();
    #pragma unroll
    for (int kk = 0; kk < 64; kk += 32) {
      s16x8 bf = fragload16(lsb, w*16, kk, l);
      #pragma unroll
      for (int m = 0; m < 4; ++m) {
        s16x8 af = fragload16(lsa, m*16, kk, l);
        acc[m] = __builtin_amdgcn_mfma_f32_16x16x32_bf16(af, bf, acc[m], 0, 0, 0);
      }
    }
    __syncthreads();
  }

  const int kq = l >> 4, lc = l & 15;
  const int voc = vrow0 + w*16 + lc;
  const float bias = Vb[voc];
  #pragma unroll
  for (int m = 0; m < 4; ++m)
    #pragma unroll
    for (int j = 0; j < 4; ++j) {
      acc[m][j] += bias;
      int brow = m*16 + kq*4 + j;
      logits[(size_t)brow*VVOC + voc] = acc[m][j];
    }
  #pragma unroll
  for (int m = 0; m < 4; ++m)
    #pragma unroll
    for (int j = 0; j < 4; ++j) {
      float v = acc[m][j];
      #pragma unroll
      for (int o = 1; o < 16; o <<= 1) v = fmaxf(v, __shfl_xor(v, o));
      if (lc == 0) red[m*16 + kq*4 + j][w] = v;
    }
  __syncthreads();
  float gmax[4][4];
  #pragma unroll
  for (int m = 0; m < 4; ++m)
    #pragma unroll
    for (int j = 0; j < 4; ++j) {
      int row = m*16 + kq*4 + j;
      gmax[m][j] = fmaxf(fmaxf(red[row][0], red[row][1]), fmaxf(red[row][2], red[row][3]));
    }
  __syncthreads();
  #pragma unroll
  for (int m = 0; m < 4; ++m)
    #pragma unroll
    for (int j = 0; j < 4; ++j) {
      float s = __expf(acc[m][j] - gmax[m][j]);
      #pragma unroll
      for (int o = 1; o < 16; o <<= 1) s += __shfl_xor(s, o);
      if (lc == 0) red[m*16 + kq*4 + j][4 + w] = s;
    }
  __syncthreads();
  if (t < 64) {
    float M = fmaxf(fmaxf(red[t][0], red[t][1]), fmaxf(red[t][2], red[t][3]));
    float S = red[t][4] + red[t][5] + red[t][6] + red[t][7];
    MAXP[blockIdx.x*64 + t] = M;
    SUMP[blockIdx.x*64 + t] = S;
  }
}

// ---------- vocab softmax normalize ----------
__global__ __launch_bounds__(256) void vnorm(
    const float* __restrict__ MAXP, const float* __restrict__ SUMP,
    float* __restrict__ logits)
{
  __shared__ float red[4];
  int b = blockIdx.x, q = blockIdx.y, t = threadIdx.x;
  float m = -INFINITY;
  for (int i = t; i < 500; i += 256) m = fmaxf(m, MAXP[i*64 + b]);
  m = blkmax(m, red, t);
  float z = 0.f;
  for (int i = t; i < 500; i += 256) z += SUMP[i*64 + b] * __expf(MAXP[i*64 + b] - m);
  z = blksum(z, red, t);
  float inv = 1.f / z;
  f32x4* p = (f32x4*)(logits + (size_t)b*VVOC + q*8000);
  for (int i = t; i < 2000; i += 256) {
    f32x4 v = p[i];
    #pragma unroll
    for (int c = 0; c < 4; ++c) v[c] = __expf(v[c] - m) * inv;
    p[i] = v;
  }
}

// ---------- combine K-split partials + biases ----------
__global__ void combineN(const float* __restrict__ P, const float* __restrict__ b1,
                         const float* __restrict__ b2, float* __restrict__ dstv,
                         int N, int total, int nseg)
{
  int i = blockIdx.x*256 + threadIdx.x;
  if (i >= total) return;
  float a = 0.f;
  for (int s = 0; s < nseg; ++s) a += P[(size_t)s*total + i];
  int c = i % N;
  if (b1) a += b1[c];
  if (b2) a += b2[c];
  dstv[i] = a;
}

// ---------- GRU gate combine ----------
__global__ void gru_gate(const float* __restrict__ GI, const float* __restrict__ GH,
                         const float* __restrict__ b_ih, const float* __restrict__ b_hh,
                         const float* __restrict__ hprev, float* __restrict__ hid,
                         float* __restrict__ concat)
{
  int i = blockIdx.x*256 + threadIdx.x;
  int b = i >> 9, h = i & 511;
  float ir=0, iz=0, inn=0, hr=0, hz=0, hn=0;
  #pragma unroll
  for (int s = 0; s < 8; ++s) {
    const float* gi = GI + (size_t)s*(64*1536) + b*1536;
    const float* gh = GH + (size_t)s*(64*1536) + b*1536;
    ir += gi[h];      iz += gi[512+h];  inn += gi[1024+h];
    hr += gh[h];      hz += gh[512+h];  hn  += gh[1024+h];
  }
  ir += b_ih[h]; iz += b_ih[512+h]; inn += b_ih[1024+h];
  hr += b_hh[h]; hz += b_hh[512+h]; hn  += b_hh[1024+h];
  float r = sigm(ir + hr), z = sigm(iz + hz);
  float n = tanhfast(inn + r*hn);
  float hv = (1.f - z)*n + z*hprev[i];
  hid[i] = hv;
  concat[b*1536 + h] = hv;
}

// ---------- masked softmax over S ----------
__global__ void softmax_s(const float* __restrict__ part, const void* __restrict__ mask,
                          const int* __restrict__ flags, float* __restrict__ attn)
{
  __shared__ float red[4];
  int b = blockIdx.x, t = threadIdx.x;
  bool isbyte = (flags[0]|flags[1]|flags[2]|flags[3]|flags[4]|flags[5]|flags[6]|flags[7]) != 0;
  float sc0, sc1 = -INFINITY;
  {
    float v = 0.f;
    #pragma unroll
    for (int p = 0; p < 8; ++p) v += part[p*MTOT + b*SS + t];
    bool mv = isbyte ? (((const unsigned char*)mask)[b*SS + t] != 0)
                     : (((const int*)mask)[b*SS + t] != 0);
    sc0 = mv ? v : -INFINITY;
  }
  int s1 = t + 256;
  if (s1 < SS) {
    float v = 0.f;
    #pragma unroll
    for (int p = 0; p < 8; ++p) v += part[p*MTOT + b*SS + s1];
    bool mv = isbyte ? (((const unsigned char*)mask)[b*SS + s1] != 0)
                     : (((const int*)mask)[b*SS + s1] != 0);
    sc1 = mv ? v : -INFINITY;
  }
  float mx = blkmax(fmaxf(sc0, sc1), red, t);
  float e0 = __expf(sc0 - mx), e1 = __expf(sc1 - mx);
  float sum = blksum(e0 + e1, red, t);
  float inv = 1.f / sum;
  attn[b*SS + t] = e0 * inv;
  if (s1 < SS) attn[b*SS + s1] = e1 * inv;
}

// ---------- context partials: CTXP[sq][b][1024] over 8 S-slices of 50 ----------
__global__ void ctx_part(const float* __restrict__ attn, const unsigned int* __restrict__ enc16,
                         float* __restrict__ CTXP)
{
  int b = blockIdx.x, dh = blockIdx.y, sq = blockIdx.z;
  int d0 = dh*512 + threadIdx.x*2;
  const float* a = attn + b*SS + sq*50;
  const unsigned int* e = enc16 + (((size_t)(b*SS + sq*50)*1024 + d0) >> 1);
  float lo = 0.f, hi = 0.f;
  #pragma unroll 5
  for (int s = 0; s < 50; ++s) {
    unsigned int u = e[(size_t)s*512];
    float av = a[s];
    lo += av * __uint_as_float(u << 16);
    hi += av * __uint_as_float(u & 0xffff0000u);
  }
  float* dst = CTXP + (size_t)sq*65536 + b*1024 + d0;
  dst[0] = lo; dst[1] = hi;
}

// ---------- ctx combine: ctx (d_out) + CONCAT[:,512:] ----------
__global__ void ctx_combine(const float* __restrict__ CTXP, float* __restrict__ ctx,
                            float* __restrict__ concat)
{
  int b = blockIdx.x;
  for (int d = threadIdx.x; d < 1024; d += 256) {
    float s = 0.f;
    #pragma unroll
    for (int q = 0; q < 8; ++q) s += CTXP[q*65536 + b*1024 + d];
    ctx[b*1024 + d] = s;
    concat[b*1536 + 512 + d] = s;
  }
}

// ---------- launch ----------
extern "C" void kernel_launch(void* const* d_in, const int* in_sizes, int n_in,
                              void* d_out, int out_size, void* d_ws, size_t ws_size,
                              hipStream_t stream) {
  (void)in_sizes; (void)n_in; (void)out_size; (void)ws_size;
  const float* x      = (const float*)d_in[0];
  const float* hprev  = (const float*)d_in[1];
  const float* enc    = (const float*)d_in[2];
  const void*  mask   = d_in[3];
  const float* w_ih   = (const float*)d_in[4];
  const float* w_hh   = (const float*)d_in[5];
  const float* b_ih   = (const float*)d_in[6];
  const float* b_hh   = (const float*)d_in[7];
  const float* Wh_w   = (const float*)d_in[8];
  const float* Wh_b   = (const float*)d_in[9];
  const float* Ws_w   = (const float*)d_in[10];
  const float* Ws_b   = (const float*)d_in[11];
  const float* vatt   = (const float*)d_in[12];
  const float* V_w    = (const float*)d_in[13];
  const float* V_b    = (const float*)d_in[14];
  const float* Vhat_w = (const float*)d_in[15];
  const float* Vhat_b = (const float*)d_in[16];

  float* out   = (float*)d_out;
  float* vocab = out;                    // [64,32000]
  float* attn  = out + 2048000;          // [64,400]
  float* ctx   = out + 2073600;          // [64,1024]
  float* hid   = out + 2139136;          // [64,512]

  float* WS     = (float*)d_ws;
  int*   FLAGS  = (int*)d_ws;            // 16 ints
  float* GI     = WS + 16;               // 8*64*1536 = 786432
  float* GH     = GI + 786432;           // 786432
  float* QP     = GH + 786432;           // 8*64*512  = 262144
  float* Q      = QP + 262144;           // 32768
  float* OUT    = Q + 32768;             // 32768
  float* PART   = OUT + 32768;           // 8*25600 = 204800
  float* MAXP   = PART + 204800;         // 32000
  float* SUMP   = MAXP + 32000;          // 32000
  float* CTXP   = SUMP + 32000;          // 8*64*1024 = 524288
  float* OUTP   = CTXP + 524288;         // 24*64*512 = 786432
  float* CONCAT = OUTP + 786432;         // 64*1536 = 98304
  float* ENDF   = CONCAT + 98304;
  size_t f32_bytes = ((size_t)((char*)ENDF - (char*)d_ws) + 15) & ~(size_t)15;
  short* ENC16 = (short*)((char*)d_ws + f32_bytes);   // 25600*1024
  short* WH16  = ENC16 + (size_t)25600*1024;          // 512*1024

  // 1. convert enc+Wh to bf16, detect mask dtype
  cvt_all<<<dim3(1864), 256, 0, stream>>>(enc, Wh_w, ENC16, WH16,
                                          (const unsigned int*)mask, 6400, FLAGS);
  // 2-3. GRU: gi/gh partials (K-split 8) then gate combine
  mfma_small<<<dim3(24, 8, 2), 256, 0, stream>>>(x, hprev, w_ih, w_hh, GI, GH, 512, 1536);
  gru_gate<<<dim3(128), 256, 0, stream>>>(GI, GH, b_ih, b_hh, hprev, hid, CONCAT);
  // 4-5. q = hid@Ws^T + Ws_b + Wh_b
  mfma_small<<<dim3(8, 8, 1), 256, 0, stream>>>(hid, hid, Ws_w, Ws_w, QP, QP, 512, 512);
  combineN<<<dim3(128), 256, 0, stream>>>(QP, Ws_b, Wh_b, Q, 512, 32768, 8);
  // 6. fused attention score GEMM (XCD-swizzled)
  score_gemm_bf16<<<dim3(800), 256, 0, stream>>>(
      (const __hip_bfloat16*)ENC16, (const __hip_bfloat16*)WH16, Q, vatt, PART);
  // 7. masked softmax over S
  softmax_s<<<dim3(64), 256, 0, stream>>>(PART, mask, FLAGS, attn);
  // 8-9. context partials (S split 8) + combine into ctx & CONCAT
  ctx_part<<<dim3(64, 2, 8), 256, 0, stream>>>(attn, (const unsigned int*)ENC16, CTXP);
  ctx_combine<<<dim3(64), 256, 0, stream>>>(CTXP, ctx, CONCAT);
  // 10-11. out = CONCAT@V_w^T + V_b  (K-split 24)
  mfma_small<<<dim3(8, 24, 1), 256, 0, stream>>>(CONCAT, CONCAT, V_w, V_w, OUTP, OUTP, 1536, 512);
  combineN<<<dim3(128), 256, 0, stream>>>(OUTP, V_b, nullptr, OUT, 512, 32768, 24);
  // 12. vocab GEMM + softmax partials
  vocab_gemm<<<dim3(500), 256, 0, stream>>>(OUT, Vhat_w, Vhat_b, vocab, MAXP, SUMP);
  // 13. softmax normalize
  vnorm<<<dim3(64, 4), 256, 0, stream>>>(MAXP, SUMP, vocab);
}

// Round 6
// 156.206 us; speedup vs baseline: 1.5788x; 1.0105x over previous
//
#include <hip/hip_runtime.h>
#include <hip/hip_bf16.h>
#include <stdint.h>

#define DI __device__ __forceinline__

using f32x4 = __attribute__((ext_vector_type(4))) float;
using s16x8 = __attribute__((ext_vector_type(8))) short;

#define BB 64
#define SS 400
#define HH 512
#define VVOC 32000
#define MTOT (BB*SS)   // 25600

// ---------- helpers ----------
DI short bf16r(float f){
  __hip_bfloat16 h = __float2bfloat16(f);
  union { __hip_bfloat16 h; short s; } u; u.h = h; return u.s;
}
DI float sigm(float x){ return 1.f/(1.f + __expf(-x)); }
DI float tanhfast(float x){ x = fminf(x, 12.f); float e = __expf(2.f*x); return (e-1.f)/(e+1.f); }

DI void gload16b(const __hip_bfloat16* g, short* l){
  __builtin_amdgcn_global_load_lds(
      (const __attribute__((address_space(1))) __hip_bfloat16*)g,
      (__attribute__((address_space(3))) short*)l, 16, 0, 0);
}

DI float blkmax(float v, float* red, int t){
  #pragma unroll
  for (int o = 32; o; o >>= 1) v = fmaxf(v, __shfl_xor(v, o));
  if ((t & 63) == 0) red[t >> 6] = v;
  __syncthreads();
  v = fmaxf(fmaxf(red[0], red[1]), fmaxf(red[2], red[3]));
  __syncthreads();
  return v;
}
DI float blksum(float v, float* red, int t){
  #pragma unroll
  for (int o = 32; o; o >>= 1) v += __shfl_xor(v, o);
  if ((t & 63) == 0) red[t >> 6] = v;
  __syncthreads();
  v = red[0] + red[1] + red[2] + red[3];
  __syncthreads();
  return v;
}

DI s16x8 cvt8(const float* src){
  f32x4 a = ((const f32x4*)src)[0];
  f32x4 b = ((const f32x4*)src)[1];
  s16x8 o;
  o[0]=bf16r(a[0]); o[1]=bf16r(a[1]); o[2]=bf16r(a[2]); o[3]=bf16r(a[3]);
  o[4]=bf16r(b[0]); o[5]=bf16r(b[1]); o[6]=bf16r(b[2]); o[7]=bf16r(b[3]);
  return o;
}

// bf16 LDS tile: row stride 64 shorts (128B), 8 chunks of 16B, slot = chunk ^ (row&7)
DI s16x8 fragload16(const short* tile, int rbase, int kk, int l){
  int r = rbase + (l & 15);
  int c = (kk >> 3) + (l >> 4);
  int slot = c ^ (r & 7);
  return *(const s16x8*)(tile + r*64 + slot*8);
}

// ---------- fused cvt (enc, Wh) + mask dtype detect ----------
__global__ __launch_bounds__(256) void cvt_all(
    const float* __restrict__ enc, const float* __restrict__ wh,
    short* __restrict__ enc16, short* __restrict__ wh16,
    const unsigned int* __restrict__ mask, int mwords, int* __restrict__ flags)
{
  int b = blockIdx.x, t = threadIdx.x;
  if (b < 1600) {
    int i = b*256 + t;
    #pragma unroll
    for (int k = 0; k < 8; ++k) {
      int idx = i + k*409600;
      ((s16x8*)enc16)[idx] = cvt8(enc + (size_t)idx*8);
    }
  } else if (b < 1856) {
    int i = (b-1600)*256 + t;
    ((s16x8*)wh16)[i] = cvt8(wh + (size_t)i*8);
  } else {
    __shared__ int f;
    if (t == 0) f = 0;
    __syncthreads();
    int loc = 0;
    for (int i = (b-1856)*256 + t; i < mwords; i += 8*256) loc |= (mask[i] > 1u) ? 1 : 0;
    if (loc) atomicOr(&f, 1);
    __syncthreads();
    if (t == 0) flags[b-1856] = f;
  }
}

// ---------- MFMA small GEMM: P[kseg] = A[64,K](k-chunk) @ W[N,K]^T(k-chunk) ----------
__global__ __launch_bounds__(256) void mfma_small(
    const float* __restrict__ A0, const float* __restrict__ A1,
    const float* __restrict__ W0, const float* __restrict__ W1,
    float* __restrict__ P0, float* __restrict__ P1,
    int K, int N)
{
  const float* A = blockIdx.z ? A1 : A0;
  const float* W = blockIdx.z ? W1 : W0;
  float*       P = blockIdx.z ? P1 : P0;
  __shared__ __align__(16) short lsa[64*64];
  __shared__ __align__(16) short lsb[64*64];
  const int t = threadIdx.x, l = t & 63, w = t >> 6;
  const int c0 = blockIdx.x*64;
  const int kbeg = blockIdx.y*64;

  #pragma unroll
  for (int q = 0; q < 2; ++q) {
    int it = q*256 + t;
    int r = it >> 3, c = it & 7;
    int slot = (c ^ (r & 7)) << 3;
    *(s16x8*)(lsa + r*64 + slot) = cvt8(A + (size_t)r*K + kbeg + c*8);
    *(s16x8*)(lsb + r*64 + slot) = cvt8(W + (size_t)(c0 + r)*K + kbeg + c*8);
  }
  __syncthreads();

  f32x4 acc[4];
  #pragma unroll
  for (int m = 0; m < 4; ++m) { f32x4 z = {0.f,0.f,0.f,0.f}; acc[m] = z; }
  #pragma unroll
  for (int kk = 0; kk < 64; kk += 32) {
    s16x8 bf = fragload16(lsb, w*16, kk, l);
    #pragma unroll
    for (int m = 0; m < 4; ++m) {
      s16x8 af = fragload16(lsa, m*16, kk, l);
      acc[m] = __builtin_amdgcn_mfma_f32_16x16x32_bf16(af, bf, acc[m], 0, 0, 0);
    }
  }
  const int kq = l >> 4, lc = l & 15;
  const int col = c0 + w*16 + lc;
  size_t pbase = (size_t)blockIdx.y * 64 * N;
  #pragma unroll
  for (int m = 0; m < 4; ++m)
    #pragma unroll
    for (int j = 0; j < 4; ++j)
      P[pbase + (size_t)(m*16 + kq*4 + j)*N + col] = acc[m][j];
}

// ---------- bf16 score GEMM, 2-phase counted-vmcnt pipeline + fused tanh-dot epilogue ----------
// STAGE addressing: LDS dest is strictly base + lane*16 within each wave-issued
// instruction (HW constraint of global_load_lds); swizzle lives in the GLOBAL src.
__global__ __launch_bounds__(256) void score_gemm_bf16(
    const __hip_bfloat16* __restrict__ A, const __hip_bfloat16* __restrict__ Bw,
    const float* __restrict__ qv, const float* __restrict__ vb, float* __restrict__ dst)
{
  __shared__ __align__(16) short lsa[2][128*64];
  __shared__ __align__(16) short lsb[2][128*64];
  const int t = threadIdx.x;
  const int l = t & 63;
  const int w = t >> 6;
  const int wm = w >> 1, wn = w & 1;
  const int phys = blockIdx.x;
  const int logical = (phys & 7)*100 + (phys >> 3);
  const int mrow = (logical >> 2) * 128;
  const int colb = logical & 3;
  const int ncol = colb * 128;

  f32x4 acc[4][4];
  #pragma unroll
  for (int m = 0; m < 4; ++m)
    #pragma unroll
    for (int n = 0; n < 4; ++n) { f32x4 z = {0.f,0.f,0.f,0.f}; acc[m][n] = z; }

  #define STAGE(buf, k0)                                                           \
    _Pragma("unroll")                                                              \
    for (int i = 0; i < 4; ++i) {                                                  \
      int ci = i*256 + t;            /* 16B-chunk index; lane-linear LDS dest */   \
      int r = ci >> 3;                                                             \
      int slot = ci & 7;                                                           \
      int c = slot ^ (r & 7);        /* pre-swizzled global source */              \
      gload16b(A + (size_t)(mrow + r)*1024 + (k0) + c*8, &lsa[buf][ci*8]);         \
      gload16b(Bw + (size_t)(ncol + r)*1024 + (k0) + c*8, &lsb[buf][ci*8]);        \
    }

  STAGE(0, 0)
  int cur = 0;
  for (int step = 0; step < 16; ++step) {
    if (step < 15) {
      STAGE(cur ^ 1, (step + 1) * 64)
      asm volatile("s_waitcnt vmcnt(8)" ::: "memory");   // keep next tile's 8 loads in flight
    } else {
      asm volatile("s_waitcnt vmcnt(0)" ::: "memory");
    }
    __builtin_amdgcn_s_barrier();
    __builtin_amdgcn_sched_barrier(0);   // pin: no LDS read hoists above the barrier
    #pragma unroll
    for (int kk = 0; kk < 64; kk += 32) {
      s16x8 bf[4];
      #pragma unroll
      for (int n = 0; n < 4; ++n) bf[n] = fragload16(lsb[cur], wn*64 + n*16, kk, l);
      #pragma unroll
      for (int m = 0; m < 4; ++m) {
        s16x8 af = fragload16(lsa[cur], wm*64 + m*16, kk, l);
        #pragma unroll
        for (int n = 0; n < 4; ++n)
          acc[m][n] = __builtin_amdgcn_mfma_f32_16x16x32_bf16(af, bf[n], acc[m][n], 0, 0, 0);
      }
    }
    __builtin_amdgcn_sched_barrier(0);   // pin: no LDS read sinks below the barrier
    __builtin_amdgcn_s_barrier();
    cur ^= 1;
  }
  #undef STAGE

  const int kq = l >> 4, lc = l & 15;
  float vv[4];
  #pragma unroll
  for (int n = 0; n < 4; ++n) vv[n] = vb[ncol + wn*64 + n*16 + lc];
  #pragma unroll
  for (int m = 0; m < 4; ++m) {
    #pragma unroll
    for (int j = 0; j < 4; ++j) {
      int r = mrow + wm*64 + m*16 + kq*4 + j;
      int b = r / SS;
      const float* qb = qv + b*HH + ncol + wn*64 + lc;
      float ps = 0.f;
      #pragma unroll
      for (int n = 0; n < 4; ++n) ps += vv[n]*tanhfast(acc[m][n][j] + qb[n*16]);
      #pragma unroll
      for (int o = 1; o < 16; o <<= 1) ps += __shfl_xor(ps, o);
      if (lc == 0) dst[(colb*2 + wn)*MTOT + r] = ps;
    }
  }
}

// ---------- vocab GEMM: logits = OUT[64,512] @ Vhat[32000,512]^T + Vb ----------
__global__ __launch_bounds__(256) void vocab_gemm(
    const float* __restrict__ OUTm, const float* __restrict__ Vhat,
    const float* __restrict__ Vb, float* __restrict__ logits,
    float* __restrict__ MAXP, float* __restrict__ SUMP)
{
  __shared__ __align__(16) short lsa[64*64];
  __shared__ __align__(16) short lsb[64*64];
  __shared__ float red[64][8];
  const int t = threadIdx.x, l = t & 63, w = t >> 6;
  const int vrow0 = blockIdx.x * 64;

  f32x4 acc[4];
  #pragma unroll
  for (int m = 0; m < 4; ++m) { f32x4 z = {0.f,0.f,0.f,0.f}; acc[m] = z; }

  for (int k0 = 0; k0 < 512; k0 += 64) {
    #pragma unroll
    for (int q = 0; q < 2; ++q) {
      int it = q*256 + t;
      int r = it >> 3, c = it & 7;
      s16x8 o = cvt8(OUTm + (size_t)r*512 + k0 + c*8);
      *(s16x8*)(lsa + r*64 + ((c ^ (r & 7)) << 3)) = o;
    }
    #pragma unroll
    for (int q = 0; q < 2; ++q) {
      int it = q*256 + t;
      int r = it >> 3, c = it & 7;
      s16x8 o = cvt8(Vhat + (size_t)(vrow0 + r)*512 + k0 + c*8);
      *(s16x8*)(lsb + r*64 + ((c ^ (r & 7)) << 3)) = o;
    }
    __syncthreads();
    #pragma unroll
    for (int kk = 0; kk < 64; kk += 32) {
      s16x8 bf = fragload16(lsb, w*16, kk, l);
      #pragma unroll
      for (int m = 0; m < 4; ++m) {
        s16x8 af = fragload16(lsa, m*16, kk, l);
        acc[m] = __builtin_amdgcn_mfma_f32_16x16x32_bf16(af, bf, acc[m], 0, 0, 0);
      }
    }
    __syncthreads();
  }

  const int kq = l >> 4, lc = l & 15;
  const int voc = vrow0 + w*16 + lc;
  const float bias = Vb[voc];
  #pragma unroll
  for (int m = 0; m < 4; ++m)
    #pragma unroll
    for (int j = 0; j < 4; ++j) {
      acc[m][j] += bias;
      int brow = m*16 + kq*4 + j;
      logits[(size_t)brow*VVOC + voc] = acc[m][j];
    }
  #pragma unroll
  for (int m = 0; m < 4; ++m)
    #pragma unroll
    for (int j = 0; j < 4; ++j) {
      float v = acc[m][j];
      #pragma unroll
      for (int o = 1; o < 16; o <<= 1) v = fmaxf(v, __shfl_xor(v, o));
      if (lc == 0) red[m*16 + kq*4 + j][w] = v;
    }
  __syncthreads();
  float gmax[4][4];
  #pragma unroll
  for (int m = 0; m < 4; ++m)
    #pragma unroll
    for (int j = 0; j < 4; ++j) {
      int row = m*16 + kq*4 + j;
      gmax[m][j] = fmaxf(fmaxf(red[row][0], red[row][1]), fmaxf(red[row][2], red[row][3]));
    }
  __syncthreads();
  #pragma unroll
  for (int m = 0; m < 4; ++m)
    #pragma unroll
    for (int j = 0; j < 4; ++j) {
      float s = __expf(acc[m][j] - gmax[m][j]);
      #pragma unroll
      for (int o = 1; o < 16; o <<= 1) s += __shfl_xor(s, o);
      if (lc == 0) red[m*16 + kq*4 + j][4 + w] = s;
    }
  __syncthreads();
  if (t < 64) {
    float M = fmaxf(fmaxf(red[t][0], red[t][1]), fmaxf(red[t][2], red[t][3]));
    float S = red[t][4] + red[t][5] + red[t][6] + red[t][7];
    MAXP[blockIdx.x*64 + t] = M;
    SUMP[blockIdx.x*64 + t] = S;
  }
}

// ---------- vocab softmax normalize ----------
__global__ __launch_bounds__(256) void vnorm(
    const float* __restrict__ MAXP, const float* __restrict__ SUMP,
    float* __restrict__ logits)
{
  __shared__ float red[4];
  int b = blockIdx.x, q = blockIdx.y, t = threadIdx.x;
  float m = -INFINITY;
  for (int i = t; i < 500; i += 256) m = fmaxf(m, MAXP[i*64 + b]);
  m = blkmax(m, red, t);
  float z = 0.f;
  for (int i = t; i < 500; i += 256) z += SUMP[i*64 + b] * __expf(MAXP[i*64 + b] - m);
  z = blksum(z, red, t);
  float inv = 1.f / z;
  f32x4* p = (f32x4*)(logits + (size_t)b*VVOC + q*8000);
  for (int i = t; i < 2000; i += 256) {
    f32x4 v = p[i];
    #pragma unroll
    for (int c = 0; c < 4; ++c) v[c] = __expf(v[c] - m) * inv;
    p[i] = v;
  }
}

// ---------- combine K-split partials + biases ----------
__global__ void combineN(const float* __restrict__ P, const float* __restrict__ b1,
                         const float* __restrict__ b2, float* __restrict__ dstv,
                         int N, int total, int nseg)
{
  int i = blockIdx.x*256 + threadIdx.x;
  if (i >= total) return;
  float a = 0.f;
  for (int s = 0; s < nseg; ++s) a += P[(size_t)s*total + i];
  int c = i % N;
  if (b1) a += b1[c];
  if (b2) a += b2[c];
  dstv[i] = a;
}

// ---------- GRU gate combine ----------
__global__ void gru_gate(const float* __restrict__ GI, const float* __restrict__ GH,
                         const float* __restrict__ b_ih, const float* __restrict__ b_hh,
                         const float* __restrict__ hprev, float* __restrict__ hid,
                         float* __restrict__ concat)
{
  int i = blockIdx.x*256 + threadIdx.x;
  int b = i >> 9, h = i & 511;
  float ir=0, iz=0, inn=0, hr=0, hz=0, hn=0;
  #pragma unroll
  for (int s = 0; s < 8; ++s) {
    const float* gi = GI + (size_t)s*(64*1536) + b*1536;
    const float* gh = GH + (size_t)s*(64*1536) + b*1536;
    ir += gi[h];      iz += gi[512+h];  inn += gi[1024+h];
    hr += gh[h];      hz += gh[512+h];  hn  += gh[1024+h];
  }
  ir += b_ih[h]; iz += b_ih[512+h]; inn += b_ih[1024+h];
  hr += b_hh[h]; hz += b_hh[512+h]; hn  += b_hh[1024+h];
  float r = sigm(ir + hr), z = sigm(iz + hz);
  float n = tanhfast(inn + r*hn);
  float hv = (1.f - z)*n + z*hprev[i];
  hid[i] = hv;
  concat[b*1536 + h] = hv;
}

// ---------- masked softmax over S ----------
__global__ void softmax_s(const float* __restrict__ part, const void* __restrict__ mask,
                          const int* __restrict__ flags, float* __restrict__ attn)
{
  __shared__ float red[4];
  int b = blockIdx.x, t = threadIdx.x;
  bool isbyte = (flags[0]|flags[1]|flags[2]|flags[3]|flags[4]|flags[5]|flags[6]|flags[7]) != 0;
  float sc0, sc1 = -INFINITY;
  {
    float v = 0.f;
    #pragma unroll
    for (int p = 0; p < 8; ++p) v += part[p*MTOT + b*SS + t];
    bool mv = isbyte ? (((const unsigned char*)mask)[b*SS + t] != 0)
                     : (((const int*)mask)[b*SS + t] != 0);
    sc0 = mv ? v : -INFINITY;
  }
  int s1 = t + 256;
  if (s1 < SS) {
    float v = 0.f;
    #pragma unroll
    for (int p = 0; p < 8; ++p) v += part[p*MTOT + b*SS + s1];
    bool mv = isbyte ? (((const unsigned char*)mask)[b*SS + s1] != 0)
                     : (((const int*)mask)[b*SS + s1] != 0);
    sc1 = mv ? v : -INFINITY;
  }
  float mx = blkmax(fmaxf(sc0, sc1), red, t);
  float e0 = __expf(sc0 - mx), e1 = __expf(sc1 - mx);
  float sum = blksum(e0 + e1, red, t);
  float inv = 1.f / sum;
  attn[b*SS + t] = e0 * inv;
  if (s1 < SS) attn[b*SS + s1] = e1 * inv;
}

// ---------- context partials: CTXP[sq][b][1024] over 8 S-slices of 50 ----------
__global__ void ctx_part(const float* __restrict__ attn, const unsigned int* __restrict__ enc16,
                         float* __restrict__ CTXP)
{
  int b = blockIdx.x, dh = blockIdx.y, sq = blockIdx.z;
  int d0 = dh*512 + threadIdx.x*2;
  const float* a = attn + b*SS + sq*50;
  const unsigned int* e = enc16 + (((size_t)(b*SS + sq*50)*1024 + d0) >> 1);
  float lo = 0.f, hi = 0.f;
  #pragma unroll 5
  for (int s = 0; s < 50; ++s) {
    unsigned int u = e[(size_t)s*512];
    float av = a[s];
    lo += av * __uint_as_float(u << 16);
    hi += av * __uint_as_float(u & 0xffff0000u);
  }
  float* dst = CTXP + (size_t)sq*65536 + b*1024 + d0;
  dst[0] = lo; dst[1] = hi;
}

// ---------- ctx combine: ctx (d_out) + CONCAT[:,512:] ----------
__global__ void ctx_combine(const float* __restrict__ CTXP, float* __restrict__ ctx,
                            float* __restrict__ concat)
{
  int b = blockIdx.x;
  for (int d = threadIdx.x; d < 1024; d += 256) {
    float s = 0.f;
    #pragma unroll
    for (int q = 0; q < 8; ++q) s += CTXP[q*65536 + b*1024 + d];
    ctx[b*1024 + d] = s;
    concat[b*1536 + 512 + d] = s;
  }
}

// ---------- launch ----------
extern "C" void kernel_launch(void* const* d_in, const int* in_sizes, int n_in,
                              void* d_out, int out_size, void* d_ws, size_t ws_size,
                              hipStream_t stream) {
  (void)in_sizes; (void)n_in; (void)out_size; (void)ws_size;
  const float* x      = (const float*)d_in[0];
  const float* hprev  = (const float*)d_in[1];
  const float* enc    = (const float*)d_in[2];
  const void*  mask   = d_in[3];
  const float* w_ih   = (const float*)d_in[4];
  const float* w_hh   = (const float*)d_in[5];
  const float* b_ih   = (const float*)d_in[6];
  const float* b_hh   = (const float*)d_in[7];
  const float* Wh_w   = (const float*)d_in[8];
  const float* Wh_b   = (const float*)d_in[9];
  const float* Ws_w   = (const float*)d_in[10];
  const float* Ws_b   = (const float*)d_in[11];
  const float* vatt   = (const float*)d_in[12];
  const float* V_w    = (const float*)d_in[13];
  const float* V_b    = (const float*)d_in[14];
  const float* Vhat_w = (const float*)d_in[15];
  const float* Vhat_b = (const float*)d_in[16];

  float* out   = (float*)d_out;
  float* vocab = out;                    // [64,32000]
  float* attn  = out + 2048000;          // [64,400]
  float* ctx   = out + 2073600;          // [64,1024]
  float* hid   = out + 2139136;          // [64,512]

  float* WS     = (float*)d_ws;
  int*   FLAGS  = (int*)d_ws;            // 16 ints
  float* GI     = WS + 16;               // 8*64*1536 = 786432
  float* GH     = GI + 786432;           // 786432
  float* QP     = GH + 786432;           // 8*64*512  = 262144
  float* Q      = QP + 262144;           // 32768
  float* OUT    = Q + 32768;             // 32768
  float* PART   = OUT + 32768;           // 8*25600 = 204800
  float* MAXP   = PART + 204800;         // 32000
  float* SUMP   = MAXP + 32000;          // 32000
  float* CTXP   = SUMP + 32000;          // 8*64*1024 = 524288
  float* OUTP   = CTXP + 524288;         // 24*64*512 = 786432
  float* CONCAT = OUTP + 786432;         // 64*1536 = 98304
  float* ENDF   = CONCAT + 98304;
  size_t f32_bytes = ((size_t)((char*)ENDF - (char*)d_ws) + 15) & ~(size_t)15;
  short* ENC16 = (short*)((char*)d_ws + f32_bytes);   // 25600*1024
  short* WH16  = ENC16 + (size_t)25600*1024;          // 512*1024

  // 1. convert enc+Wh to bf16, detect mask dtype
  cvt_all<<<dim3(1864), 256, 0, stream>>>(enc, Wh_w, ENC16, WH16,
                                          (const unsigned int*)mask, 6400, FLAGS);
  // 2-3. GRU: gi/gh partials (K-split 8) then gate combine
  mfma_small<<<dim3(24, 8, 2), 256, 0, stream>>>(x, hprev, w_ih, w_hh, GI, GH, 512, 1536);
  gru_gate<<<dim3(128), 256, 0, stream>>>(GI, GH, b_ih, b_hh, hprev, hid, CONCAT);
  // 4-5. q = hid@Ws^T + Ws_b + Wh_b
  mfma_small<<<dim3(8, 8, 1), 256, 0, stream>>>(hid, hid, Ws_w, Ws_w, QP, QP, 512, 512);
  combineN<<<dim3(128), 256, 0, stream>>>(QP, Ws_b, Wh_b, Q, 512, 32768, 8);
  // 6. fused attention score GEMM (XCD-swizzled, 2-phase pipelined)
  score_gemm_bf16<<<dim3(800), 256, 0, stream>>>(
      (const __hip_bfloat16*)ENC16, (const __hip_bfloat16*)WH16, Q, vatt, PART);
  // 7. masked softmax over S
  softmax_s<<<dim3(64), 256, 0, stream>>>(PART, mask, FLAGS, attn);
  // 8-9. context partials (S split 8) + combine into ctx & CONCAT
  ctx_part<<<dim3(64, 2, 8), 256, 0, stream>>>(attn, (const unsigned int*)ENC16, CTXP);
  ctx_combine<<<dim3(64), 256, 0, stream>>>(CTXP, ctx, CONCAT);
  // 10-11. out = CONCAT@V_w^T + V_b  (K-split 24)
  mfma_small<<<dim3(8, 24, 1), 256, 0, stream>>>(CONCAT, CONCAT, V_w, V_w, OUTP, OUTP, 1536, 512);
  combineN<<<dim3(128), 256, 0, stream>>>(OUTP, V_b, nullptr, OUT, 512, 32768, 24);
  // 12. vocab GEMM + softmax partials
  vocab_gemm<<<dim3(500), 256, 0, stream>>>(OUT, Vhat_w, Vhat_b, vocab, MAXP, SUMP);
  // 13. softmax normalize
  vnorm<<<dim3(64, 4), 256, 0, stream>>>(MAXP, SUMP, vocab);
}